// Round 12
// baseline (12820.024 us; speedup 1.0000x reference)
//
#include <hip/hip_runtime.h>
#include <stdint.h>
#include <stddef.h>

typedef __attribute__((ext_vector_type(8))) short short8;
typedef __attribute__((ext_vector_type(4))) short short4_t;
typedef __attribute__((ext_vector_type(8))) unsigned short ushort8_t;
typedef __attribute__((ext_vector_type(4))) unsigned short ushort4_t;
typedef __attribute__((ext_vector_type(4))) float f32x4;
typedef __attribute__((ext_vector_type(4))) unsigned uint4_t;
typedef __attribute__((ext_vector_type(2))) unsigned uint2_t;

// workspace layout (bytes)
#define XG_BYTES  (134217728ull)          // xg: [1024 t][4 g][1024 n][16 b] bf16
#define HS_BYTES  (33587200ull)           // hs: [1025 t][16 b][1024 k] bf16
#define PAD_OFF   (XG_BYTES + HS_BYTES)
#define WT_OFF    (PAD_OFF + 32768ull)    // Wt: [9][1024 n][1024 k] bf16

#define SENT 0x7FC07FC0u                  // bf16 NaN pair — finite data never equals this

__device__ __forceinline__ unsigned short f2b(float f){
  unsigned u = __builtin_bit_cast(unsigned, f);
  u += 0x7fffu + ((u >> 16) & 1u);
  return (unsigned short)(u >> 16);
}
__device__ __forceinline__ float b2f(unsigned short b){
  unsigned u = ((unsigned)b) << 16;
  return __builtin_bit_cast(float, u);
}
__device__ __forceinline__ float sigm(float x){ return 1.0f / (1.0f + __expf(-x)); }
__device__ __forceinline__ float tanh_(float x){ return 2.0f / (1.0f + __expf(-2.0f*x)) - 1.0f; }

// ---- issue 8 PLAIN cached dwordx4 loads, NO wait ---------------------------
#define ISSUE8P(p, A) asm volatile( \
    "global_load_dwordx4 %0, %8, off\n\t" \
    "global_load_dwordx4 %1, %8, off offset:64\n\t" \
    "global_load_dwordx4 %2, %8, off offset:128\n\t" \
    "global_load_dwordx4 %3, %8, off offset:192\n\t" \
    "global_load_dwordx4 %4, %8, off offset:256\n\t" \
    "global_load_dwordx4 %5, %8, off offset:320\n\t" \
    "global_load_dwordx4 %6, %8, off offset:384\n\t" \
    "global_load_dwordx4 %7, %8, off offset:448" \
    : "=&v"((A)[0]), "=&v"((A)[1]), "=&v"((A)[2]), "=&v"((A)[3]), \
      "=&v"((A)[4]), "=&v"((A)[5]), "=&v"((A)[6]), "=&v"((A)[7]) \
    : "v"(p) : "memory")

__device__ __forceinline__ void st_u32_mall(unsigned* p, unsigned v){
  asm volatile("global_store_dword %0, %1, off sc0 sc1"
               :: "v"(p), "v"(v) : "memory");
}

// ---------------- weight transpose+convert: W[k][n] f32 -> Wt[n][k] bf16 ----
__global__ __launch_bounds__(256) void k_prep(
    const float* __restrict__ w0, const float* __restrict__ w1,
    const float* __restrict__ w2, const float* __restrict__ w3,
    const float* __restrict__ w4, const float* __restrict__ w5,
    const float* __restrict__ w6, const float* __restrict__ w7,
    const float* __restrict__ w8, unsigned short* __restrict__ wt)
{
  const int z = blockIdx.z;
  const float* W = (z==0)?w0:(z==1)?w1:(z==2)?w2:(z==3)?w3:(z==4)?w4:
                   (z==5)?w5:(z==6)?w6:(z==7)?w7:w8;
  unsigned short* out = wt + (size_t)z*1024*1024;
  __shared__ float tile[64][65];
  const int k0 = blockIdx.x*64, n0 = blockIdx.y*64;
  const int tid = threadIdx.x;
  {
    const int kk = tid >> 2, nn0 = (tid & 3) * 16;
    const float* src = W + (size_t)(k0+kk)*1024 + n0 + nn0;
    #pragma unroll
    for (int j=0;j<16;j+=4){
      f32x4 v = *(const f32x4*)(src + j);
      tile[kk][nn0+j+0]=v[0]; tile[kk][nn0+j+1]=v[1];
      tile[kk][nn0+j+2]=v[2]; tile[kk][nn0+j+3]=v[3];
    }
  }
  __syncthreads();
  {
    const int nn = tid >> 2, kk0 = (tid & 3) * 16;
    ushort8_t a, b;
    #pragma unroll
    for (int j=0;j<8;++j){ a[j]=f2b(tile[kk0+j][nn]); b[j]=f2b(tile[kk0+8+j][nn]); }
    unsigned short* dst = out + (size_t)(n0+nn)*1024 + k0 + kk0;
    *(ushort8_t*)dst = a;
    *(ushort8_t*)(dst+8) = b;
  }
}

// ---------------- h0 -> hs[0] bf16 (write-through) ---------------------------
__global__ void k_init(const float* __restrict__ h0, unsigned short* __restrict__ hs){
  const int i = blockIdx.x*256 + threadIdx.x;
  unsigned v = (unsigned)f2b(h0[i]);
  asm volatile("global_store_short %0, %1, off sc0 sc1"
               :: "v"(hs + i), "v"(v) : "memory");
}

// ---------------- sentinel-fill xg (all) + hs[1..1024] (write-through) -------
__global__ void k_fill(unsigned* __restrict__ xgw, unsigned* __restrict__ hsw){
  const size_t i = (size_t)blockIdx.x*256 + threadIdx.x;   // 10,485,760 threads
  uint4_t v = (uint4_t){SENT, SENT, SENT, SENT};
  if (i < 8388608ull){
    asm volatile("global_store_dwordx4 %0, %1, off sc0 sc1"
                 :: "v"(xgw + i*4), "v"(v) : "memory");
  } else {
    asm volatile("global_store_dwordx4 %0, %1, off sc0 sc1"
                 :: "v"(hsw + 8192 + (i - 8388608ull)*4), "v"(v) : "memory");
  }
}

// ---------------- fused mega-kernel ------------------------------------------
// WGs 0..63:   persistent recurrence — wave-autonomous: each wave owns 4 cols x
//              4 gates as the 16 N-slots of ONE MFMA tile, full K=1024 in regs
//              (wf[32]); no barrier, no LDS, no cross-wave reduce.
// WGs 64..255: xproj tiles then post tiles (unchanged from R11).
__global__ __launch_bounds__(256,1) void k_mega(
    const float* __restrict__ xF, const float* __restrict__ xI,
    const float* __restrict__ xZ, const float* __restrict__ xO,
    const float* __restrict__ bF, const float* __restrict__ bI,
    const float* __restrict__ bZ, const float* __restrict__ bO,
    const unsigned short* __restrict__ wt,   // [9][1024][1024] bf16
    const float* __restrict__ bfh, const float* __restrict__ bih,
    const float* __restrict__ bzh, const float* __restrict__ boh,
    const float* __restrict__ c0,
    unsigned short* __restrict__ xg,
    unsigned short* __restrict__ hs,
    const float* __restrict__ bpost,
    float* __restrict__ y,
    float* __restrict__ oc, float* __restrict__ oh)
{
  __shared__ __align__(16) char smem[32768];
  const int tid  = threadIdx.x;
  const int lane = tid & 63, wv = tid >> 6;
  const int l15  = lane & 15, lg = lane >> 4;

  if (blockIdx.x < 64){
    // ==================== wave-autonomous recurrence ====================
    const unsigned short* WtR = wt + (size_t)5*1048576;
    const int wg  = blockIdx.x;
    const int n0  = wg*16 + wv*4;        // this wave's 4 columns
    const int g_  = l15 >> 2;            // this lane's gate (B-col = (g,c))
    const int c_  = l15 & 3;             // this lane's column within the 4
    const int col = n0 + c_;

    // B fragments: W[g_][col][k], 32 chunks of k (lane k-slice lg*8..+7)
    short8 wf[32];
    {
      const unsigned short* wp = WtR + (size_t)g_*1048576 + (size_t)col*1024 + lg*8;
      #pragma unroll
      for (int ch=0; ch<32; ++ch)
        wf[ch] = *(const short8*)(wp + ch*32);
    }

    float cst[4];
    #pragma unroll
    for (int r=0;r<4;++r) cst[r] = c0[(size_t)(lg*4+r)*1024 + col];
    const float bias_[4] = {bfh[col], bih[col], bzh[col], boh[col]};

    unsigned* hsw = (unsigned*)hs;
    float hvout[4] = {0.f,0.f,0.f,0.f};

    for (int t=0; t<1024; ++t){
      // xq: 4 gates at this lane's col, rows lg*4..+3 (plain loads)
      short4_t xq[4];
      {
        const unsigned short* xb = xg + (size_t)((t*4)*1024 + col)*16 + lg*4;
        asm volatile(
          "global_load_dwordx2 %0, %4, off\n\t"
          "global_load_dwordx2 %1, %5, off\n\t"
          "global_load_dwordx2 %2, %6, off\n\t"
          "global_load_dwordx2 %3, %7, off"
          : "=&v"(xq[0]), "=&v"(xq[1]), "=&v"(xq[2]), "=&v"(xq[3])
          : "v"(xb), "v"(xb + 16384), "v"(xb + 32768), "v"(xb + 49152)
          : "memory");
      }

      // A fragments: h row l15, all 32 k-chunks (plain, XCD-L2-shared)
      const unsigned short* hp = hs + (size_t)t*16384 + (size_t)l15*1024 + lg*8;
      short8 a[32];
      ISSUE8P(hp,        a);
      ISSUE8P(hp +  256, a + 8);
      ISSUE8P(hp +  512, a + 16);
      ISSUE8P(hp +  768, a + 24);
      asm volatile("s_waitcnt vmcnt(0)" ::: "memory");
      __builtin_amdgcn_sched_barrier(0);

      // sentinel chunk-retry (sc0sc1 bypasses any stale L2 line)
      {
        bool bad[32]; bool any = false;
        #pragma unroll
        for (int ch=0; ch<32; ++ch){
          uint4_t q = __builtin_bit_cast(uint4_t, a[ch]);
          bad[ch] = (q[0]==SENT)||(q[1]==SENT)||(q[2]==SENT)||(q[3]==SENT);
          any = any | bad[ch];
        }
        while (__any(any)){
          __builtin_amdgcn_s_sleep(1);
          #pragma unroll
          for (int ch=0; ch<32; ++ch)
            if (bad[ch])
              asm volatile("global_load_dwordx4 %0, %1, off sc0 sc1"
                           : "+v"(a[ch]) : "v"(hp + ch*32) : "memory");
          asm volatile("s_waitcnt vmcnt(0)" ::: "memory");
          __builtin_amdgcn_sched_barrier(0);
          any = false;
          #pragma unroll
          for (int ch=0; ch<32; ++ch){
            uint4_t q = __builtin_bit_cast(uint4_t, a[ch]);
            bad[ch] = (q[0]==SENT)||(q[1]==SENT)||(q[2]==SENT)||(q[3]==SENT);
            any = any | bad[ch];
          }
        }
      }
      // xq sentinel gate (xproj runs concurrently)
      {
        bool xb_[4]; bool anyx = false;
        #pragma unroll
        for (int m=0; m<4; ++m){
          uint2_t u = __builtin_bit_cast(uint2_t, xq[m]);
          xb_[m] = (u[0]==SENT)||(u[1]==SENT);
          anyx = anyx | xb_[m];
        }
        while (__any(anyx)){
          __builtin_amdgcn_s_sleep(2);
          const unsigned short* xb = xg + (size_t)((t*4)*1024 + col)*16 + lg*4;
          #pragma unroll
          for (int m=0; m<4; ++m)
            if (xb_[m])
              asm volatile("global_load_dwordx2 %0, %1, off sc0 sc1"
                           : "+v"(xq[m]) : "v"(xb + m*16384) : "memory");
          asm volatile("s_waitcnt vmcnt(0)" ::: "memory");
          __builtin_amdgcn_sched_barrier(0);
          anyx = false;
          #pragma unroll
          for (int m=0; m<4; ++m){
            uint2_t u = __builtin_bit_cast(uint2_t, xq[m]);
            xb_[m] = (u[0]==SENT)||(u[1]==SENT);
            anyx = anyx | xb_[m];
          }
        }
      }

      // 32 MFMAs into one 16x16 tile: D[row][(g,c)] ; 4 interleaved chains
      f32x4 ac0 = (f32x4){0,0,0,0}, ac1 = (f32x4){0,0,0,0};
      f32x4 ac2 = (f32x4){0,0,0,0}, ac3 = (f32x4){0,0,0,0};
      #pragma unroll
      for (int ch=0; ch<32; ch+=4){
        ac0 = __builtin_amdgcn_mfma_f32_16x16x32_bf16(a[ch+0], wf[ch+0], ac0, 0,0,0);
        ac1 = __builtin_amdgcn_mfma_f32_16x16x32_bf16(a[ch+1], wf[ch+1], ac1, 0,0,0);
        ac2 = __builtin_amdgcn_mfma_f32_16x16x32_bf16(a[ch+2], wf[ch+2], ac2, 0,0,0);
        ac3 = __builtin_amdgcn_mfma_f32_16x16x32_bf16(a[ch+3], wf[ch+3], ac3, 0,0,0);
      }
      f32x4 accv = (ac0 + ac1) + (ac2 + ac3);   // this lane: gate g_, col c_, rows lg*4+r

      // gather all 4 gates for (rows, col): lanes {c_+4g} hold gates g
      f32x4 vB, vC, vD;
      #pragma unroll
      for (int r=0;r<4;++r){
        vB[r] = __shfl_xor(accv[r], 4);   // gate g_^1
        vC[r] = __shfl_xor(accv[r], 8);   // gate g_^2
        vD[r] = __shfl_xor(vB[r],   8);   // gate g_^3
      }
      f32x4 rg[4];
      #pragma unroll
      for (int m=0;m<4;++m){
        const int s = g_ ^ m;
        rg[m] = (s==0) ? accv : (s==1) ? vB : (s==2) ? vC : vD;
      }

      // gate 4 rows x 1 col (4x lane redundancy across gates — cheap, uncoupled)
      #pragma unroll
      for (int r=0;r<4;++r){
        const int sh = r*16;
        float pf = rg[0][r] + b2f((unsigned short)(__builtin_bit_cast(unsigned long long, xq[0]) >> sh)) + bias_[0];
        float pi = rg[1][r] + b2f((unsigned short)(__builtin_bit_cast(unsigned long long, xq[1]) >> sh)) + bias_[1];
        float pz = rg[2][r] + b2f((unsigned short)(__builtin_bit_cast(unsigned long long, xq[2]) >> sh)) + bias_[2];
        float po = rg[3][r] + b2f((unsigned short)(__builtin_bit_cast(unsigned long long, xq[3]) >> sh)) + bias_[3];
        float fg = sigm(pf), ig = sigm(pi), zg = tanh_(pz), og = sigm(po);
        float cn = fg*cst[r] + ig*zg;
        cst[r] = cn;
        hvout[r] = og * tanh_(cn);
      }

      // pack bf16 col-pairs via lane^1; lanes (g_==0, even c_) store 4 words
      #pragma unroll
      for (int r=0;r<4;++r){
        unsigned m  = (unsigned)f2b(hvout[r]);
        unsigned nb = (unsigned)__shfl_xor(m, 1);
        if (g_ == 0 && (c_ & 1) == 0){
          unsigned word = m | (nb << 16);
          unsigned* pw = hsw + (size_t)(t+1)*8192 + (size_t)(lg*4+r)*512 + (col >> 1);
          st_u32_mall(pw, word);
        }
      }
    }

    if (g_ == 0){
      #pragma unroll
      for (int r=0;r<4;++r){
        oc[(size_t)(lg*4+r)*1024 + col] = cst[r];
        oh[(size_t)(lg*4+r)*1024 + col] = hvout[r];
      }
    }
    return;
  }

  // ==================== xproj + post (WGs 64..255) ====================
  unsigned short* AsmB = (unsigned short*)smem;            // [128*32]
  unsigned short* BsmB = (unsigned short*)(smem + 8192);   // [128*32]
  const int wid = blockIdx.x - 64;
  const int wy = wv >> 1, wx = wv & 1;
  const int rr = tid >> 1, kq = tid & 1;
  const int s0 = kq*2;
  unsigned short* aw0 = &AsmB[rr*32 + (((s0  ) ^ (rr&3))<<3)];
  unsigned short* aw1 = &AsmB[rr*32 + (((s0+1) ^ (rr&3))<<3)];
  unsigned short* bw0 = &BsmB[rr*32 + (((s0  ) ^ (rr&3))<<3)];
  unsigned short* bw1 = &BsmB[rr*32 + (((s0+1) ^ (rr&3))<<3)];

  // ---- xproj tiles: idx = tm*32 + tn*4 + g, tm-major ----
  for (int idx = wid; idx < 4096; idx += 192){
    const int tm = idx >> 5, rmn = idx & 31, tn = rmn >> 2, g = rmn & 3;
    const float* X  = (g==0)?xF:(g==1)?xI:(g==2)?xZ:xO;
    const float* Bp = (g==0)?bF:(g==1)?bI:(g==2)?bZ:bO;
    const unsigned short* Wg = wt + (size_t)g*1048576;

    const int ar = tm*128 + rr;
    const int ab = ar & 15, as_ = ar >> 4;
    const float* aptr = X + ((size_t)ab*1024 + as_)*1024 + kq*16;
    const unsigned short* bp_ = Wg + (size_t)(tn*128 + rr)*1024 + kq*16;

    f32x4 acc[4][4];
    #pragma unroll
    for (int m=0;m<4;++m)
      #pragma unroll
      for (int q=0;q<4;++q) acc[m][q] = (f32x4){0.f,0.f,0.f,0.f};

    for (int k0=0; k0<1024; k0+=32){
      const float* ap = aptr + k0;
      f32x4 v0 = *(const f32x4*)(ap + 0);
      f32x4 v1 = *(const f32x4*)(ap + 4);
      f32x4 v2 = *(const f32x4*)(ap + 8);
      f32x4 v3 = *(const f32x4*)(ap + 12);
      ushort8_t pa, pb;
      #pragma unroll
      for (int j=0;j<4;++j){ pa[j]=f2b(v0[j]); pa[4+j]=f2b(v1[j]); pb[j]=f2b(v2[j]); pb[4+j]=f2b(v3[j]); }
      *(ushort8_t*)aw0 = pa;
      *(ushort8_t*)aw1 = pb;
      ushort8_t q0 = *(const ushort8_t*)(bp_ + k0);
      ushort8_t q1 = *(const ushort8_t*)(bp_ + k0 + 8);
      *(ushort8_t*)bw0 = q0;
      *(ushort8_t*)bw1 = q1;
      __syncthreads();

      short8 af[4], bf_[4];
      #pragma unroll
      for (int m=0;m<4;++m){
        int row = wy*64 + m*16 + l15;
        af[m] = *(const short8*)&AsmB[row*32 + ((lg ^ (row&3))<<3)];
      }
      #pragma unroll
      for (int q=0;q<4;++q){
        int row = wx*64 + q*16 + l15;
        bf_[q] = *(const short8*)&BsmB[row*32 + ((lg ^ (row&3))<<3)];
      }
      #pragma unroll
      for (int m=0;m<4;++m)
        #pragma unroll
        for (int q=0;q<4;++q)
          acc[m][q] = __builtin_amdgcn_mfma_f32_16x16x32_bf16(af[m], bf_[q], acc[m][q], 0,0,0);
      __syncthreads();
    }

    #pragma unroll
    for (int m=0;m<4;++m){
      const int t = tm*8 + wy*4 + m;
      #pragma unroll
      for (int q=0;q<4;++q){
        const int n = tn*128 + wx*64 + q*16 + l15;
        const float bias = Bp[n];
        f32x4 v = acc[m][q];
        ushort4_t pk;
        #pragma unroll
        for (int r=0;r<4;++r) pk[r] = f2b(v[r] + bias);
        uint2_t w2 = __builtin_bit_cast(uint2_t, pk);
        unsigned short* dst = xg + (size_t)((t*4+g)*1024 + n)*16 + lg*4;
        asm volatile("global_store_dwordx2 %0, %1, off sc0 sc1"
                     :: "v"(dst), "v"(w2) : "memory");
      }
    }
  }

  // ---- post tiles: idx = tm*8 + tn, tm-major; A staging gated on hs ----
  for (int idx = wid; idx < 1024; idx += 192){
    const int tm = idx >> 3, tn = idx & 7;
    const unsigned short* aptr = hs + 16384 + (size_t)(tm*128 + rr)*1024 + kq*16;
    const unsigned short* bp_  = wt + (size_t)4*1048576 + (size_t)(tn*128 + rr)*1024 + kq*16;

    f32x4 acc[4][4];
    #pragma unroll
    for (int m=0;m<4;++m)
      #pragma unroll
      for (int q=0;q<4;++q) acc[m][q] = (f32x4){0.f,0.f,0.f,0.f};

    for (int k0=0; k0<1024; k0+=32){
      ushort8_t a0, a1;
      asm volatile(
        "global_load_dwordx4 %0, %2, off\n\t"
        "global_load_dwordx4 %1, %3, off\n\t"
        "s_waitcnt vmcnt(0)"
        : "=&v"(a0), "=&v"(a1)
        : "v"(aptr + k0), "v"(aptr + k0 + 8) : "memory");
      __builtin_amdgcn_sched_barrier(0);
      {
        uint4_t q0 = __builtin_bit_cast(uint4_t, a0);
        uint4_t q1 = __builtin_bit_cast(uint4_t, a1);
        bool b0 = (q0[0]==SENT)||(q0[1]==SENT)||(q0[2]==SENT)||(q0[3]==SENT);
        bool b1 = (q1[0]==SENT)||(q1[1]==SENT)||(q1[2]==SENT)||(q1[3]==SENT);
        while (__any(b0 | b1)){
          __builtin_amdgcn_s_sleep(8);
          if (b0) asm volatile("global_load_dwordx4 %0, %1, off sc0 sc1"
                               : "+v"(a0) : "v"(aptr + k0) : "memory");
          if (b1) asm volatile("global_load_dwordx4 %0, %1, off sc0 sc1"
                               : "+v"(a1) : "v"(aptr + k0 + 8) : "memory");
          asm volatile("s_waitcnt vmcnt(0)" ::: "memory");
          __builtin_amdgcn_sched_barrier(0);
          q0 = __builtin_bit_cast(uint4_t, a0);
          q1 = __builtin_bit_cast(uint4_t, a1);
          b0 = (q0[0]==SENT)||(q0[1]==SENT)||(q0[2]==SENT)||(q0[3]==SENT);
          b1 = (q1[0]==SENT)||(q1[1]==SENT)||(q1[2]==SENT)||(q1[3]==SENT);
        }
      }
      *(ushort8_t*)aw0 = a0;
      *(ushort8_t*)aw1 = a1;
      ushort8_t q0v = *(const ushort8_t*)(bp_ + k0);
      ushort8_t q1v = *(const ushort8_t*)(bp_ + k0 + 8);
      *(ushort8_t*)bw0 = q0v;
      *(ushort8_t*)bw1 = q1v;
      __syncthreads();

      short8 af[4], bf_[4];
      #pragma unroll
      for (int m=0;m<4;++m){
        int row = wy*64 + m*16 + l15;
        af[m] = *(const short8*)&AsmB[row*32 + ((lg ^ (row&3))<<3)];
      }
      #pragma unroll
      for (int q=0;q<4;++q){
        int row = wx*64 + q*16 + l15;
        bf_[q] = *(const short8*)&BsmB[row*32 + ((lg ^ (row&3))<<3)];
      }
      #pragma unroll
      for (int m=0;m<4;++m)
        #pragma unroll
        for (int q=0;q<4;++q)
          acc[m][q] = __builtin_amdgcn_mfma_f32_16x16x32_bf16(af[m], bf_[q], acc[m][q], 0,0,0);
      __syncthreads();
    }

    #pragma unroll
    for (int m=0;m<4;++m){
      const int s = tm*8 + wy*4 + m;
      #pragma unroll
      for (int q=0;q<4;++q){
        const int n = tn*128 + wx*64 + q*16 + l15;
        const float bias = bpost[n];
        f32x4 v = acc[m][q];
        #pragma unroll
        for (int r=0;r<4;++r){
          const int b = lg*4 + r;
          y[((size_t)b << 20) + ((size_t)s << 10) + n] = v[r] + bias;
        }
      }
    }
  }
}

extern "C" void kernel_launch(void* const* d_in, const int* in_sizes, int n_in,
                              void* d_out, int out_size, void* d_ws, size_t ws_size,
                              hipStream_t stream)
{
  const float* f_in = (const float*)d_in[0];
  const float* i_in = (const float*)d_in[1];
  const float* z_in = (const float*)d_in[2];
  const float* o_in = (const float*)d_in[3];
  const float* c0   = (const float*)d_in[4];
  const float* h0   = (const float*)d_in[5];
  const float* W_Fx = (const float*)d_in[6];  const float* b_Fx = (const float*)d_in[7];
  const float* W_Ix = (const float*)d_in[8];  const float* b_Ix = (const float*)d_in[9];
  const float* W_Zx = (const float*)d_in[10]; const float* b_Zx = (const float*)d_in[11];
  const float* W_Ox = (const float*)d_in[12]; const float* b_Ox = (const float*)d_in[13];
  const float* W_Fh = (const float*)d_in[14]; const float* b_Fh = (const float*)d_in[15];
  const float* W_Ih = (const float*)d_in[16]; const float* b_Ih = (const float*)d_in[17];
  const float* W_Zh = (const float*)d_in[18]; const float* b_Zh = (const float*)d_in[19];
  const float* W_Oh = (const float*)d_in[20]; const float* b_Oh = (const float*)d_in[21];
  const float* W_post = (const float*)d_in[22]; const float* b_post = (const float*)d_in[23];

  char* ws = (char*)d_ws;
  unsigned short* xg = (unsigned short*)(ws);
  unsigned short* hs = (unsigned short*)(ws + XG_BYTES);
  unsigned short* wt = (unsigned short*)(ws + WT_OFF);

  float* y  = (float*)d_out;
  float* oc = y + 16777216;   // 16*1024*1024
  float* oh = oc + 16384;

  k_prep<<<dim3(16,16,9), 256, 0, stream>>>(W_Fx, W_Ix, W_Zx, W_Ox, W_post,
                                            W_Fh, W_Ih, W_Zh, W_Oh, wt);
  k_init<<<64, 256, 0, stream>>>(h0, hs);
  k_fill<<<40960, 256, 0, stream>>>((unsigned*)xg, (unsigned*)hs);
  k_mega<<<256, 256, 0, stream>>>(f_in, i_in, z_in, o_in,
                                  b_Fx, b_Ix, b_Zx, b_Ox,
                                  wt,
                                  b_Fh, b_Ih, b_Zh, b_Oh,
                                  c0, xg, hs, b_post, y, oc, oh);
}

// Round 13
// 3564.300 us; speedup vs baseline: 3.5968x; 3.5968x over previous
//
#include <hip/hip_runtime.h>
#include <stdint.h>
#include <stddef.h>

typedef __attribute__((ext_vector_type(8))) short short8;
typedef __attribute__((ext_vector_type(4))) short short4_t;
typedef __attribute__((ext_vector_type(8))) unsigned short ushort8_t;
typedef __attribute__((ext_vector_type(4))) unsigned short ushort4_t;
typedef __attribute__((ext_vector_type(4))) float f32x4;
typedef __attribute__((ext_vector_type(4))) unsigned uint4_t;
typedef __attribute__((ext_vector_type(2))) unsigned uint2_t;

// workspace layout (bytes)
#define XG_BYTES  (134217728ull)          // xg: [1024 t][4 g][1024 n][16 b] bf16
#define HS_BYTES  (33587200ull)           // hs: [1025 t][16 b][1024 k] bf16
#define PAD_OFF   (XG_BYTES + HS_BYTES)
#define WT_OFF    (PAD_OFF + 32768ull)    // Wt: [9][1024 n][1024 k] bf16

#define SENT 0x7FC07FC0u                  // bf16 NaN pair — finite data never equals this

__device__ __forceinline__ unsigned short f2b(float f){
  unsigned u = __builtin_bit_cast(unsigned, f);
  u += 0x7fffu + ((u >> 16) & 1u);
  return (unsigned short)(u >> 16);
}
__device__ __forceinline__ float b2f(unsigned short b){
  unsigned u = ((unsigned)b) << 16;
  return __builtin_bit_cast(float, u);
}
__device__ __forceinline__ float sigm(float x){ return 1.0f / (1.0f + __expf(-x)); }
__device__ __forceinline__ float tanh_(float x){ return 2.0f / (1.0f + __expf(-2.0f*x)) - 1.0f; }

// ---- PLAIN cached 8x dwordx4 bulk load (L2-allocating, XCD-shared) --------
__device__ __forceinline__ void ld_h8_plain(const unsigned short* p, short8* a){
  asm volatile(
    "global_load_dwordx4 %0, %8, off\n\t"
    "global_load_dwordx4 %1, %8, off offset:64\n\t"
    "global_load_dwordx4 %2, %8, off offset:128\n\t"
    "global_load_dwordx4 %3, %8, off offset:192\n\t"
    "global_load_dwordx4 %4, %8, off offset:256\n\t"
    "global_load_dwordx4 %5, %8, off offset:320\n\t"
    "global_load_dwordx4 %6, %8, off offset:384\n\t"
    "global_load_dwordx4 %7, %8, off offset:448\n\t"
    "s_waitcnt vmcnt(0)"
    : "=&v"(a[0]), "=&v"(a[1]), "=&v"(a[2]), "=&v"(a[3]),
      "=&v"(a[4]), "=&v"(a[5]), "=&v"(a[6]), "=&v"(a[7])
    : "v"(p) : "memory");
}
__device__ __forceinline__ void st_u32_mall(unsigned* p, unsigned v){
  asm volatile("global_store_dword %0, %1, off sc0 sc1"
               :: "v"(p), "v"(v) : "memory");
}

// ---------------- weight transpose+convert: W[k][n] f32 -> Wt[n][k] bf16 ----
__global__ __launch_bounds__(256) void k_prep(
    const float* __restrict__ w0, const float* __restrict__ w1,
    const float* __restrict__ w2, const float* __restrict__ w3,
    const float* __restrict__ w4, const float* __restrict__ w5,
    const float* __restrict__ w6, const float* __restrict__ w7,
    const float* __restrict__ w8, unsigned short* __restrict__ wt)
{
  const int z = blockIdx.z;
  const float* W = (z==0)?w0:(z==1)?w1:(z==2)?w2:(z==3)?w3:(z==4)?w4:
                   (z==5)?w5:(z==6)?w6:(z==7)?w7:w8;
  unsigned short* out = wt + (size_t)z*1024*1024;
  __shared__ float tile[64][65];
  const int k0 = blockIdx.x*64, n0 = blockIdx.y*64;
  const int tid = threadIdx.x;
  {
    const int kk = tid >> 2, nn0 = (tid & 3) * 16;
    const float* src = W + (size_t)(k0+kk)*1024 + n0 + nn0;
    #pragma unroll
    for (int j=0;j<16;j+=4){
      f32x4 v = *(const f32x4*)(src + j);
      tile[kk][nn0+j+0]=v[0]; tile[kk][nn0+j+1]=v[1];
      tile[kk][nn0+j+2]=v[2]; tile[kk][nn0+j+3]=v[3];
    }
  }
  __syncthreads();
  {
    const int nn = tid >> 2, kk0 = (tid & 3) * 16;
    ushort8_t a, b;
    #pragma unroll
    for (int j=0;j<8;++j){ a[j]=f2b(tile[kk0+j][nn]); b[j]=f2b(tile[kk0+8+j][nn]); }
    unsigned short* dst = out + (size_t)(n0+nn)*1024 + k0 + kk0;
    *(ushort8_t*)dst = a;
    *(ushort8_t*)(dst+8) = b;
  }
}

// ---------------- h0 -> hs[0] bf16 (write-through) ---------------------------
__global__ void k_init(const float* __restrict__ h0, unsigned short* __restrict__ hs){
  const int i = blockIdx.x*256 + threadIdx.x;
  unsigned v = (unsigned)f2b(h0[i]);
  asm volatile("global_store_short %0, %1, off sc0 sc1"
               :: "v"(hs + i), "v"(v) : "memory");
}

// ---------------- sentinel-fill xg (all) + hs[1..1024] (write-through) -------
__global__ void k_fill(unsigned* __restrict__ xgw, unsigned* __restrict__ hsw){
  const size_t i = (size_t)blockIdx.x*256 + threadIdx.x;   // 10,485,760 threads
  uint4_t v = (uint4_t){SENT, SENT, SENT, SENT};
  if (i < 8388608ull){
    asm volatile("global_store_dwordx4 %0, %1, off sc0 sc1"
                 :: "v"(xgw + i*4), "v"(v) : "memory");
  } else {
    asm volatile("global_store_dwordx4 %0, %1, off sc0 sc1"
                 :: "v"(hsw + 8192 + (i - 8388608ull)*4), "v"(v) : "memory");
  }
}

// ---------------- fused mega-kernel ------------------------------------------
// WGs 0..63:   persistent recurrence (R11 core + component-plane partials,
//              own-row-first gating, post-store xq prefetch).
// WGs 64..255: xproj tiles then post tiles (unchanged from R11).
__global__ __launch_bounds__(256,1) void k_mega(
    const float* __restrict__ xF, const float* __restrict__ xI,
    const float* __restrict__ xZ, const float* __restrict__ xO,
    const float* __restrict__ bF, const float* __restrict__ bI,
    const float* __restrict__ bZ, const float* __restrict__ bO,
    const unsigned short* __restrict__ wt,   // [9][1024][1024] bf16
    const float* __restrict__ bfh, const float* __restrict__ bih,
    const float* __restrict__ bzh, const float* __restrict__ boh,
    const float* __restrict__ c0,
    unsigned short* __restrict__ xg,
    unsigned short* __restrict__ hs,
    const float* __restrict__ bpost,
    float* __restrict__ y,
    float* __restrict__ oc, float* __restrict__ oh)
{
  __shared__ __align__(16) char smem[32768];
  const int tid  = threadIdx.x;
  const int lane = tid & 63, wv = tid >> 6;
  const int l15  = lane & 15, lg = lane >> 4;

  if (blockIdx.x < 64){
    // ==================== recurrence ====================
    typedef float PartT[4][4][4][64];        // [wave][gate][comp][lane]
    PartT* part = (PartT*)smem;              // part[2][...] = 32 KB

    const unsigned short* WtR = wt + (size_t)5*1048576;
    const int wg   = blockIdx.x;
    const int n    = wg*16 + l15;
    const int rown = lg*4 + wv;              // own batch row
    const int sh   = wv * 16;                // component-extract shift

    short8 wf[4][8];
    #pragma unroll
    for (int g=0; g<4; ++g){
      const unsigned short* wp = WtR + (size_t)g*1048576 + (size_t)n*1024 + wv*256 + lg*8;
      #pragma unroll
      for (int c=0; c<8; ++c)
        wf[g][c] = *(const short8*)(wp + c*32);
    }

    float cst[4]; float bias[4];
    bias[0]=bfh[n]; bias[1]=bih[n]; bias[2]=bzh[n]; bias[3]=boh[n];
    #pragma unroll
    for (int r=0;r<4;++r) cst[r] = c0[(size_t)(lg*4+r)*1024 + n];

    unsigned* hsw = (unsigned*)hs;
    const int koff = l15*1024 + wv*256 + lg*8;

    // xq prologue (t = 0), plain loads
    short4_t xq[4];
    {
      const unsigned short* xb = xg + (size_t)n*16 + lg*4;
      asm volatile(
        "global_load_dwordx2 %0, %4, off\n\t"
        "global_load_dwordx2 %1, %5, off\n\t"
        "global_load_dwordx2 %2, %6, off\n\t"
        "global_load_dwordx2 %3, %7, off\n\t"
        "s_waitcnt vmcnt(0)"
        : "=&v"(xq[0]), "=&v"(xq[1]), "=&v"(xq[2]), "=&v"(xq[3])
        : "v"(xb), "v"(xb + 16384), "v"(xb + 32768), "v"(xb + 49152)
        : "memory");
      __builtin_amdgcn_sched_barrier(0);
    }

    float hvv[4] = {0.f,0.f,0.f,0.f};
    for (int t=0; t<1024; ++t){
      // 1. speculative bulk h load: PLAIN (L2 XCD-shared); sc0sc1 chunk retry
      const unsigned short* hp = hs + (size_t)t*16384 + koff;
      short8 a[8];
      ld_h8_plain(hp, a);
      {
        bool bad[8]; bool any = false;
        #pragma unroll
        for (int c=0;c<8;++c){
          uint4_t q = __builtin_bit_cast(uint4_t, a[c]);
          bad[c] = (q[0]==SENT)||(q[1]==SENT)||(q[2]==SENT)||(q[3]==SENT);
          any = any | bad[c];
        }
        while (__any(any)){
          __builtin_amdgcn_s_sleep(1);
          #pragma unroll
          for (int c=0;c<8;++c)
            if (bad[c])
              asm volatile("global_load_dwordx4 %0, %1, off sc0 sc1"
                           : "+v"(a[c]) : "v"(hp + c*32) : "memory");
          asm volatile("s_waitcnt vmcnt(0)" ::: "memory");
          __builtin_amdgcn_sched_barrier(0);
          any = false;
          #pragma unroll
          for (int c=0;c<8;++c){
            uint4_t q = __builtin_bit_cast(uint4_t, a[c]);
            bad[c] = (q[0]==SENT)||(q[1]==SENT)||(q[2]==SENT)||(q[3]==SENT);
            any = any | bad[c];
          }
        }
      }
      // 2. xq sentinel gate on the prefetched registers
      {
        bool xb_[4]; bool anyx = false;
        #pragma unroll
        for (int g=0; g<4; ++g){
          uint2_t u = __builtin_bit_cast(uint2_t, xq[g]);
          xb_[g] = (u[0]==SENT)||(u[1]==SENT);
          anyx = anyx | xb_[g];
        }
        while (__any(anyx)){
          __builtin_amdgcn_s_sleep(2);
          const unsigned short* xb = xg + (size_t)((t*4)*1024 + n)*16 + lg*4;
          #pragma unroll
          for (int g=0; g<4; ++g)
            if (xb_[g])
              asm volatile("global_load_dwordx2 %0, %1, off sc0 sc1"
                           : "+v"(xq[g]) : "v"(xb + g*16384) : "memory");
          asm volatile("s_waitcnt vmcnt(0)" ::: "memory");
          __builtin_amdgcn_sched_barrier(0);
          anyx = false;
          #pragma unroll
          for (int g=0; g<4; ++g){
            uint2_t u = __builtin_bit_cast(uint2_t, xq[g]);
            xb_[g] = (u[0]==SENT)||(u[1]==SENT);
            anyx = anyx | xb_[g];
          }
        }
      }

      // 3. MFMA
      f32x4 acc[4];
      #pragma unroll
      for (int g=0;g<4;++g) acc[g] = (f32x4){0.f,0.f,0.f,0.f};
      #pragma unroll
      for (int c=0;c<8;++c){
        acc[0] = __builtin_amdgcn_mfma_f32_16x16x32_bf16(a[c], wf[0][c], acc[0], 0,0,0);
        acc[1] = __builtin_amdgcn_mfma_f32_16x16x32_bf16(a[c], wf[1][c], acc[1], 0,0,0);
        acc[2] = __builtin_amdgcn_mfma_f32_16x16x32_bf16(a[c], wf[2][c], acc[2], 0,0,0);
        acc[3] = __builtin_amdgcn_mfma_f32_16x16x32_bf16(a[c], wf[3][c], acc[3], 0,0,0);
      }

      // 4. partial store as component planes + single barrier
      const int pb = t & 1;
      #pragma unroll
      for (int g=0;g<4;++g)
        #pragma unroll
        for (int cm=0;cm<4;++cm)
          part[pb][wv][g][cm][lane] = acc[g][cm];
      __syncthreads();

      // 5. OWN-ROW critical path: reduce comp wv only (16 scalar reads), gate, store
      {
        float rg0 = (part[pb][0][0][wv][lane] + part[pb][1][0][wv][lane])
                  + (part[pb][2][0][wv][lane] + part[pb][3][0][wv][lane]);
        float rg1 = (part[pb][0][1][wv][lane] + part[pb][1][1][wv][lane])
                  + (part[pb][2][1][wv][lane] + part[pb][3][1][wv][lane]);
        float rg2 = (part[pb][0][2][wv][lane] + part[pb][1][2][wv][lane])
                  + (part[pb][2][2][wv][lane] + part[pb][3][2][wv][lane]);
        float rg3 = (part[pb][0][3][wv][lane] + part[pb][1][3][wv][lane])
                  + (part[pb][2][3][wv][lane] + part[pb][3][3][wv][lane]);
        float pf = rg0 + b2f((unsigned short)(__builtin_bit_cast(unsigned long long, xq[0]) >> sh)) + bias[0];
        float pi = rg1 + b2f((unsigned short)(__builtin_bit_cast(unsigned long long, xq[1]) >> sh)) + bias[1];
        float pz = rg2 + b2f((unsigned short)(__builtin_bit_cast(unsigned long long, xq[2]) >> sh)) + bias[2];
        float po = rg3 + b2f((unsigned short)(__builtin_bit_cast(unsigned long long, xq[3]) >> sh)) + bias[3];
        float fg = sigm(pf), ig = sigm(pi), zg = tanh_(pz), og = sigm(po);
        float cn = fg*cst[wv] + ig*zg;
        cst[wv] = cn;
        float hv = og * tanh_(cn);
        hvv[wv] = hv;
        unsigned m  = (unsigned)f2b(hv);
        unsigned nb = (unsigned)__shfl_xor(m, 1);
        if ((l15 & 1) == 0){
          unsigned word = m | (nb << 16);
          unsigned* pw = hsw + (size_t)(t+1)*8192 + (size_t)rown*512 + (n >> 1);
          st_u32_mall(pw, word);
        }
      }

      // 6. xq(t+1) prefetch (plain, issued before tail so it flies under it)
      short4_t xqn[4];
      {
        const int tn_ = (t < 1023) ? (t+1) : t;
        const unsigned short* xb = xg + (size_t)((tn_*4)*1024 + n)*16 + lg*4;
        asm volatile(
          "global_load_dwordx2 %0, %4, off\n\t"
          "global_load_dwordx2 %1, %5, off\n\t"
          "global_load_dwordx2 %2, %6, off\n\t"
          "global_load_dwordx2 %3, %7, off"
          : "=&v"(xqn[0]), "=&v"(xqn[1]), "=&v"(xqn[2]), "=&v"(xqn[3])
          : "v"(xb), "v"(xb + 16384), "v"(xb + 32768), "v"(xb + 49152)
          : "memory");
      }

      // 7. tail: remaining rows (cell-state carry only), off critical path
      #pragma unroll
      for (int r=0;r<4;++r){
        if (r == wv) continue;
        float rg0 = (part[pb][0][0][r][lane] + part[pb][1][0][r][lane])
                  + (part[pb][2][0][r][lane] + part[pb][3][0][r][lane]);
        float rg1 = (part[pb][0][1][r][lane] + part[pb][1][1][r][lane])
                  + (part[pb][2][1][r][lane] + part[pb][3][1][r][lane]);
        float rg2 = (part[pb][0][2][r][lane] + part[pb][1][2][r][lane])
                  + (part[pb][2][2][r][lane] + part[pb][3][2][r][lane]);
        float rg3 = (part[pb][0][3][r][lane] + part[pb][1][3][r][lane])
                  + (part[pb][2][3][r][lane] + part[pb][3][3][r][lane]);
        float pf = rg0 + b2f((unsigned short)xq[0][r]) + bias[0];
        float pi = rg1 + b2f((unsigned short)xq[1][r]) + bias[1];
        float pz = rg2 + b2f((unsigned short)xq[2][r]) + bias[2];
        float po = rg3 + b2f((unsigned short)xq[3][r]) + bias[3];
        float fg = sigm(pf), ig = sigm(pi), zg = tanh_(pz), og = sigm(po);
        float cn = fg*cst[r] + ig*zg;
        cst[r] = cn;
        hvv[r] = og * tanh_(cn);
      }

      // 8. rotate xq pipeline
      #pragma unroll
      for (int g=0; g<4; ++g) xq[g] = xqn[g];
    }

    if (wv == 0){
      #pragma unroll
      for (int r=0;r<4;++r){
        oc[(size_t)(lg*4+r)*1024 + n] = cst[r];
        oh[(size_t)(lg*4+r)*1024 + n] = hvv[r];
      }
    }
    return;
  }

  // ==================== xproj + post (WGs 64..255) ====================
  unsigned short* AsmB = (unsigned short*)smem;            // [128*32]
  unsigned short* BsmB = (unsigned short*)(smem + 8192);   // [128*32]
  const int wid = blockIdx.x - 64;
  const int wy = wv >> 1, wx = wv & 1;
  const int rr = tid >> 1, kq = tid & 1;
  const int s0 = kq*2;
  unsigned short* aw0 = &AsmB[rr*32 + (((s0  ) ^ (rr&3))<<3)];
  unsigned short* aw1 = &AsmB[rr*32 + (((s0+1) ^ (rr&3))<<3)];
  unsigned short* bw0 = &BsmB[rr*32 + (((s0  ) ^ (rr&3))<<3)];
  unsigned short* bw1 = &BsmB[rr*32 + (((s0+1) ^ (rr&3))<<3)];

  // ---- xproj tiles: idx = tm*32 + tn*4 + g, tm-major ----
  for (int idx = wid; idx < 4096; idx += 192){
    const int tm = idx >> 5, rmn = idx & 31, tn = rmn >> 2, g = rmn & 3;
    const float* X  = (g==0)?xF:(g==1)?xI:(g==2)?xZ:xO;
    const float* Bp = (g==0)?bF:(g==1)?bI:(g==2)?bZ:bO;
    const unsigned short* Wg = wt + (size_t)g*1048576;

    const int ar = tm*128 + rr;
    const int ab = ar & 15, as_ = ar >> 4;
    const float* aptr = X + ((size_t)ab*1024 + as_)*1024 + kq*16;
    const unsigned short* bp_ = Wg + (size_t)(tn*128 + rr)*1024 + kq*16;

    f32x4 acc[4][4];
    #pragma unroll
    for (int m=0;m<4;++m)
      #pragma unroll
      for (int q=0;q<4;++q) acc[m][q] = (f32x4){0.f,0.f,0.f,0.f};

    for (int k0=0; k0<1024; k0+=32){
      const float* ap = aptr + k0;
      f32x4 v0 = *(const f32x4*)(ap + 0);
      f32x4 v1 = *(const f32x4*)(ap + 4);
      f32x4 v2 = *(const f32x4*)(ap + 8);
      f32x4 v3 = *(const f32x4*)(ap + 12);
      ushort8_t pa, pb;
      #pragma unroll
      for (int j=0;j<4;++j){ pa[j]=f2b(v0[j]); pa[4+j]=f2b(v1[j]); pb[j]=f2b(v2[j]); pb[4+j]=f2b(v3[j]); }
      *(ushort8_t*)aw0 = pa;
      *(ushort8_t*)aw1 = pb;
      ushort8_t q0 = *(const ushort8_t*)(bp_ + k0);
      ushort8_t q1 = *(const ushort8_t*)(bp_ + k0 + 8);
      *(ushort8_t*)bw0 = q0;
      *(ushort8_t*)bw1 = q1;
      __syncthreads();

      short8 af[4], bf_[4];
      #pragma unroll
      for (int m=0;m<4;++m){
        int row = wy*64 + m*16 + l15;
        af[m] = *(const short8*)&AsmB[row*32 + ((lg ^ (row&3))<<3)];
      }
      #pragma unroll
      for (int q=0;q<4;++q){
        int row = wx*64 + q*16 + l15;
        bf_[q] = *(const short8*)&BsmB[row*32 + ((lg ^ (row&3))<<3)];
      }
      #pragma unroll
      for (int m=0;m<4;++m)
        #pragma unroll
        for (int q=0;q<4;++q)
          acc[m][q] = __builtin_amdgcn_mfma_f32_16x16x32_bf16(af[m], bf_[q], acc[m][q], 0,0,0);
      __syncthreads();
    }

    #pragma unroll
    for (int m=0;m<4;++m){
      const int t = tm*8 + wy*4 + m;
      #pragma unroll
      for (int q=0;q<4;++q){
        const int n = tn*128 + wx*64 + q*16 + l15;
        const float bias = Bp[n];
        f32x4 v = acc[m][q];
        ushort4_t pk;
        #pragma unroll
        for (int r=0;r<4;++r) pk[r] = f2b(v[r] + bias);
        uint2_t w2 = __builtin_bit_cast(uint2_t, pk);
        unsigned short* dst = xg + (size_t)((t*4+g)*1024 + n)*16 + lg*4;
        asm volatile("global_store_dwordx2 %0, %1, off sc0 sc1"
                     :: "v"(dst), "v"(w2) : "memory");
      }
    }
  }

  // ---- post tiles: idx = tm*8 + tn, tm-major; A staging gated on hs ----
  for (int idx = wid; idx < 1024; idx += 192){
    const int tm = idx >> 3, tn = idx & 7;
    const unsigned short* aptr = hs + 16384 + (size_t)(tm*128 + rr)*1024 + kq*16;
    const unsigned short* bp_  = wt + (size_t)4*1048576 + (size_t)(tn*128 + rr)*1024 + kq*16;

    f32x4 acc[4][4];
    #pragma unroll
    for (int m=0;m<4;++m)
      #pragma unroll
      for (int q=0;q<4;++q) acc[m][q] = (f32x4){0.f,0.f,0.f,0.f};

    for (int k0=0; k0<1024; k0+=32){
      ushort8_t a0, a1;
      asm volatile(
        "global_load_dwordx4 %0, %2, off\n\t"
        "global_load_dwordx4 %1, %3, off\n\t"
        "s_waitcnt vmcnt(0)"
        : "=&v"(a0), "=&v"(a1)
        : "v"(aptr + k0), "v"(aptr + k0 + 8) : "memory");
      __builtin_amdgcn_sched_barrier(0);
      {
        uint4_t q0 = __builtin_bit_cast(uint4_t, a0);
        uint4_t q1 = __builtin_bit_cast(uint4_t, a1);
        bool b0 = (q0[0]==SENT)||(q0[1]==SENT)||(q0[2]==SENT)||(q0[3]==SENT);
        bool b1 = (q1[0]==SENT)||(q1[1]==SENT)||(q1[2]==SENT)||(q1[3]==SENT);
        while (__any(b0 | b1)){
          __builtin_amdgcn_s_sleep(8);
          if (b0) asm volatile("global_load_dwordx4 %0, %1, off sc0 sc1"
                               : "+v"(a0) : "v"(aptr + k0) : "memory");
          if (b1) asm volatile("global_load_dwordx4 %0, %1, off sc0 sc1"
                               : "+v"(a1) : "v"(aptr + k0 + 8) : "memory");
          asm volatile("s_waitcnt vmcnt(0)" ::: "memory");
          __builtin_amdgcn_sched_barrier(0);
          q0 = __builtin_bit_cast(uint4_t, a0);
          q1 = __builtin_bit_cast(uint4_t, a1);
          b0 = (q0[0]==SENT)||(q0[1]==SENT)||(q0[2]==SENT)||(q0[3]==SENT);
          b1 = (q1[0]==SENT)||(q1[1]==SENT)||(q1[2]==SENT)||(q1[3]==SENT);
        }
      }
      *(ushort8_t*)aw0 = a0;
      *(ushort8_t*)aw1 = a1;
      ushort8_t q0v = *(const ushort8_t*)(bp_ + k0);
      ushort8_t q1v = *(const ushort8_t*)(bp_ + k0 + 8);
      *(ushort8_t*)bw0 = q0v;
      *(ushort8_t*)bw1 = q1v;
      __syncthreads();

      short8 af[4], bf_[4];
      #pragma unroll
      for (int m=0;m<4;++m){
        int row = wy*64 + m*16 + l15;
        af[m] = *(const short8*)&AsmB[row*32 + ((lg ^ (row&3))<<3)];
      }
      #pragma unroll
      for (int q=0;q<4;++q){
        int row = wx*64 + q*16 + l15;
        bf_[q] = *(const short8*)&BsmB[row*32 + ((lg ^ (row&3))<<3)];
      }
      #pragma unroll
      for (int m=0;m<4;++m)
        #pragma unroll
        for (int q=0;q<4;++q)
          acc[m][q] = __builtin_amdgcn_mfma_f32_16x16x32_bf16(af[m], bf_[q], acc[m][q], 0,0,0);
      __syncthreads();
    }

    #pragma unroll
    for (int m=0;m<4;++m){
      const int s = tm*8 + wy*4 + m;
      #pragma unroll
      for (int q=0;q<4;++q){
        const int n = tn*128 + wx*64 + q*16 + l15;
        const float bias = bpost[n];
        f32x4 v = acc[m][q];
        #pragma unroll
        for (int r=0;r<4;++r){
          const int b = lg*4 + r;
          y[((size_t)b << 20) + ((size_t)s << 10) + n] = v[r] + bias;
        }
      }
    }
  }
}

extern "C" void kernel_launch(void* const* d_in, const int* in_sizes, int n_in,
                              void* d_out, int out_size, void* d_ws, size_t ws_size,
                              hipStream_t stream)
{
  const float* f_in = (const float*)d_in[0];
  const float* i_in = (const float*)d_in[1];
  const float* z_in = (const float*)d_in[2];
  const float* o_in = (const float*)d_in[3];
  const float* c0   = (const float*)d_in[4];
  const float* h0   = (const float*)d_in[5];
  const float* W_Fx = (const float*)d_in[6];  const float* b_Fx = (const float*)d_in[7];
  const float* W_Ix = (const float*)d_in[8];  const float* b_Ix = (const float*)d_in[9];
  const float* W_Zx = (const float*)d_in[10]; const float* b_Zx = (const float*)d_in[11];
  const float* W_Ox = (const float*)d_in[12]; const float* b_Ox = (const float*)d_in[13];
  const float* W_Fh = (const float*)d_in[14]; const float* b_Fh = (const float*)d_in[15];
  const float* W_Ih = (const float*)d_in[16]; const float* b_Ih = (const float*)d_in[17];
  const float* W_Zh = (const float*)d_in[18]; const float* b_Zh = (const float*)d_in[19];
  const float* W_Oh = (const float*)d_in[20]; const float* b_Oh = (const float*)d_in[21];
  const float* W_post = (const float*)d_in[22]; const float* b_post = (const float*)d_in[23];

  char* ws = (char*)d_ws;
  unsigned short* xg = (unsigned short*)(ws);
  unsigned short* hs = (unsigned short*)(ws + XG_BYTES);
  unsigned short* wt = (unsigned short*)(ws + WT_OFF);

  float* y  = (float*)d_out;
  float* oc = y + 16777216;   // 16*1024*1024
  float* oh = oc + 16384;

  k_prep<<<dim3(16,16,9), 256, 0, stream>>>(W_Fx, W_Ix, W_Zx, W_Ox, W_post,
                                            W_Fh, W_Ih, W_Zh, W_Oh, wt);
  k_init<<<64, 256, 0, stream>>>(h0, hs);
  k_fill<<<40960, 256, 0, stream>>>((unsigned*)xg, (unsigned*)hs);
  k_mega<<<256, 256, 0, stream>>>(f_in, i_in, z_in, o_in,
                                  b_Fx, b_Ix, b_Zx, b_Ox,
                                  wt,
                                  b_Fh, b_Ih, b_Zh, b_Oh,
                                  c0, xg, hs, b_post, y, oc, oh);
}

// Round 14
// 3402.908 us; speedup vs baseline: 3.7674x; 1.0474x over previous
//
#include <hip/hip_runtime.h>
#include <stdint.h>
#include <stddef.h>

typedef __attribute__((ext_vector_type(8))) short short8;
typedef __attribute__((ext_vector_type(4))) short short4_t;
typedef __attribute__((ext_vector_type(8))) unsigned short ushort8_t;
typedef __attribute__((ext_vector_type(4))) unsigned short ushort4_t;
typedef __attribute__((ext_vector_type(4))) float f32x4;
typedef __attribute__((ext_vector_type(4))) unsigned uint4_t;
typedef __attribute__((ext_vector_type(2))) unsigned uint2_t;

// workspace layout (bytes)
#define XG_BYTES  (134217728ull)          // xg: [1024 t][4 g][1024 n][16 b] bf16
#define HS_BYTES  (33587200ull)           // hs: [1025 t][16 b][1024 k] bf16
#define PAD_OFF   (XG_BYTES + HS_BYTES)
#define WT_OFF    (PAD_OFF + 32768ull)    // Wt: [9][1024 n][1024 k] bf16

#define SENT 0x7FC07FC0u                  // bf16 NaN pair — finite data never equals this

__device__ __forceinline__ unsigned short f2b(float f){
  unsigned u = __builtin_bit_cast(unsigned, f);
  u += 0x7fffu + ((u >> 16) & 1u);
  return (unsigned short)(u >> 16);
}
__device__ __forceinline__ float b2f(unsigned short b){
  unsigned u = ((unsigned)b) << 16;
  return __builtin_bit_cast(float, u);
}
__device__ __forceinline__ float sigm(float x){ return 1.0f / (1.0f + __expf(-x)); }
__device__ __forceinline__ float tanh_(float x){ return 2.0f / (1.0f + __expf(-2.0f*x)) - 1.0f; }

// ---- direct coherence-point 8x dwordx4 bulk load (sc0 sc1) -----------------
__device__ __forceinline__ void ld_h8_mall(const unsigned short* p, short8* a){
  asm volatile(
    "global_load_dwordx4 %0, %8, off sc0 sc1\n\t"
    "global_load_dwordx4 %1, %8, off offset:64 sc0 sc1\n\t"
    "global_load_dwordx4 %2, %8, off offset:128 sc0 sc1\n\t"
    "global_load_dwordx4 %3, %8, off offset:192 sc0 sc1\n\t"
    "global_load_dwordx4 %4, %8, off offset:256 sc0 sc1\n\t"
    "global_load_dwordx4 %5, %8, off offset:320 sc0 sc1\n\t"
    "global_load_dwordx4 %6, %8, off offset:384 sc0 sc1\n\t"
    "global_load_dwordx4 %7, %8, off offset:448 sc0 sc1\n\t"
    "s_waitcnt vmcnt(0)"
    : "=&v"(a[0]), "=&v"(a[1]), "=&v"(a[2]), "=&v"(a[3]),
      "=&v"(a[4]), "=&v"(a[5]), "=&v"(a[6]), "=&v"(a[7])
    : "v"(p) : "memory");
}
__device__ __forceinline__ void st_u32_mall(unsigned* p, unsigned v){
  asm volatile("global_store_dword %0, %1, off sc0 sc1"
               :: "v"(p), "v"(v) : "memory");
}

// ---------------- weight transpose+convert: W[k][n] f32 -> Wt[n][k] bf16 ----
__global__ __launch_bounds__(256) void k_prep(
    const float* __restrict__ w0, const float* __restrict__ w1,
    const float* __restrict__ w2, const float* __restrict__ w3,
    const float* __restrict__ w4, const float* __restrict__ w5,
    const float* __restrict__ w6, const float* __restrict__ w7,
    const float* __restrict__ w8, unsigned short* __restrict__ wt)
{
  const int z = blockIdx.z;
  const float* W = (z==0)?w0:(z==1)?w1:(z==2)?w2:(z==3)?w3:(z==4)?w4:
                   (z==5)?w5:(z==6)?w6:(z==7)?w7:w8;
  unsigned short* out = wt + (size_t)z*1024*1024;
  __shared__ float tile[64][65];
  const int k0 = blockIdx.x*64, n0 = blockIdx.y*64;
  const int tid = threadIdx.x;
  {
    const int kk = tid >> 2, nn0 = (tid & 3) * 16;
    const float* src = W + (size_t)(k0+kk)*1024 + n0 + nn0;
    #pragma unroll
    for (int j=0;j<16;j+=4){
      f32x4 v = *(const f32x4*)(src + j);
      tile[kk][nn0+j+0]=v[0]; tile[kk][nn0+j+1]=v[1];
      tile[kk][nn0+j+2]=v[2]; tile[kk][nn0+j+3]=v[3];
    }
  }
  __syncthreads();
  {
    const int nn = tid >> 2, kk0 = (tid & 3) * 16;
    ushort8_t a, b;
    #pragma unroll
    for (int j=0;j<8;++j){ a[j]=f2b(tile[kk0+j][nn]); b[j]=f2b(tile[kk0+8+j][nn]); }
    unsigned short* dst = out + (size_t)(n0+nn)*1024 + k0 + kk0;
    *(ushort8_t*)dst = a;
    *(ushort8_t*)(dst+8) = b;
  }
}

// ---------------- h0 -> hs[0] bf16 (plain; kernel-end flush publishes) ------
__global__ void k_init(const float* __restrict__ h0, unsigned short* __restrict__ hs){
  const int i = blockIdx.x*256 + threadIdx.x;
  hs[i] = f2b(h0[i]);
}

// ---------------- sentinel-fill xg (all) + hs[1..1024] (plain) ---------------
__global__ void k_fill(unsigned* __restrict__ xgw, unsigned* __restrict__ hsw){
  const size_t i = (size_t)blockIdx.x*256 + threadIdx.x;   // 10,485,760 threads
  uint4_t v = (uint4_t){SENT, SENT, SENT, SENT};
  if (i < 8388608ull){
    *(uint4_t*)(xgw + i*4) = v;
  } else {
    *(uint4_t*)(hsw + 8192 + (i - 8388608ull)*4) = v;
  }
}

// ---------------- fused mega-kernel ------------------------------------------
// WGs 0..63:   persistent recurrence (R5 core: sc0sc1 spec load + full-reload
//              retry; redundant gating on all waves; single barrier/step).
// WGs 64..255: xproj tiles (tm-major, sc0sc1 writes) then post tiles
//              (tm-major, hs staging sentinel-gated with backoff).
__global__ __launch_bounds__(256,1) void k_mega(
    const float* __restrict__ xF, const float* __restrict__ xI,
    const float* __restrict__ xZ, const float* __restrict__ xO,
    const float* __restrict__ bF, const float* __restrict__ bI,
    const float* __restrict__ bZ, const float* __restrict__ bO,
    const unsigned short* __restrict__ wt,   // [9][1024][1024] bf16
    const float* __restrict__ bfh, const float* __restrict__ bih,
    const float* __restrict__ bzh, const float* __restrict__ boh,
    const float* __restrict__ c0,
    unsigned short* __restrict__ xg,
    unsigned short* __restrict__ hs,
    const float* __restrict__ bpost,
    float* __restrict__ y,
    float* __restrict__ oc, float* __restrict__ oh)
{
  __shared__ __align__(16) char smem[32768];
  const int tid  = threadIdx.x;
  const int lane = tid & 63, wv = tid >> 6;
  const int l15  = lane & 15, lg = lane >> 4;

  if (blockIdx.x < 64){
    // ==================== recurrence (R5 core) ====================
    typedef f32x4 PartT[4][4][64];
    PartT* part = (PartT*)smem;              // part[2][4][4][64]

    const unsigned short* WtR = wt + (size_t)5*1048576;
    const int wg = blockIdx.x;
    const int n  = wg*16 + l15;

    short8 wf[4][8];
    #pragma unroll
    for (int g=0; g<4; ++g){
      const unsigned short* wp = WtR + (size_t)g*1048576 + (size_t)n*1024 + wv*256 + lg*8;
      #pragma unroll
      for (int c=0; c<8; ++c)
        wf[g][c] = *(const short8*)(wp + c*32);
    }

    float cst[4]; float bias[4];
    bias[0]=bfh[n]; bias[1]=bih[n]; bias[2]=bzh[n]; bias[3]=boh[n];
    #pragma unroll
    for (int r=0;r<4;++r) cst[r] = c0[(size_t)(lg*4+r)*1024 + n];

    unsigned* hsw = (unsigned*)hs;
    const int koff = l15*1024 + wv*256 + lg*8;

    float hv = 0.f;
    for (int t=0; t<1024; ++t){
      // xg[t] loads (plain, in flight with bulk load); sentinel-gated below
      short4_t xq[4];
      {
        const unsigned short* xb = xg + (size_t)((t*4)*1024 + n)*16 + lg*4;
        asm volatile(
          "global_load_dwordx2 %0, %4, off\n\t"
          "global_load_dwordx2 %1, %5, off\n\t"
          "global_load_dwordx2 %2, %6, off\n\t"
          "global_load_dwordx2 %3, %7, off"
          : "=&v"(xq[0]), "=&v"(xq[1]), "=&v"(xq[2]), "=&v"(xq[3])
          : "v"(xb), "v"(xb + 16384), "v"(xb + 32768), "v"(xb + 49152)
          : "memory");
      }

      // speculative bulk h load: direct sc0sc1; full-reload retry on sentinel
      const unsigned short* hp = hs + (size_t)t*16384 + koff;
      short8 a[8];
      ld_h8_mall(hp, a);
      for(;;){
        bool bad = false;
        #pragma unroll
        for (int c=0;c<8;++c){
          uint4_t q = __builtin_bit_cast(uint4_t, a[c]);
          bad |= (q[0]==SENT)|(q[1]==SENT)|(q[2]==SENT)|(q[3]==SENT);
        }
        if (!__any(bad)) break;
        __builtin_amdgcn_s_sleep(1);
        ld_h8_mall(hp, a);
      }
      // xq sentinel gate (xproj runs concurrently)
      {
        bool xb_[4]; bool anyx = false;
        #pragma unroll
        for (int g=0; g<4; ++g){
          uint2_t u = __builtin_bit_cast(uint2_t, xq[g]);
          xb_[g] = (u[0]==SENT)||(u[1]==SENT);
          anyx = anyx | xb_[g];
        }
        while (__any(anyx)){
          __builtin_amdgcn_s_sleep(2);
          const unsigned short* xb = xg + (size_t)((t*4)*1024 + n)*16 + lg*4;
          #pragma unroll
          for (int g=0; g<4; ++g)
            if (xb_[g])
              asm volatile("global_load_dwordx2 %0, %1, off sc0 sc1"
                           : "+v"(xq[g]) : "v"(xb + g*16384) : "memory");
          asm volatile("s_waitcnt vmcnt(0)" ::: "memory");
          __builtin_amdgcn_sched_barrier(0);
          anyx = false;
          #pragma unroll
          for (int g=0; g<4; ++g){
            uint2_t u = __builtin_bit_cast(uint2_t, xq[g]);
            xb_[g] = (u[0]==SENT)||(u[1]==SENT);
            anyx = anyx | xb_[g];
          }
        }
      }

      f32x4 acc[4];
      #pragma unroll
      for (int g=0;g<4;++g) acc[g] = (f32x4){0.f,0.f,0.f,0.f};
      #pragma unroll
      for (int c=0;c<8;++c){
        acc[0] = __builtin_amdgcn_mfma_f32_16x16x32_bf16(a[c], wf[0][c], acc[0], 0,0,0);
        acc[1] = __builtin_amdgcn_mfma_f32_16x16x32_bf16(a[c], wf[1][c], acc[1], 0,0,0);
        acc[2] = __builtin_amdgcn_mfma_f32_16x16x32_bf16(a[c], wf[2][c], acc[2], 0,0,0);
        acc[3] = __builtin_amdgcn_mfma_f32_16x16x32_bf16(a[c], wf[3][c], acc[3], 0,0,0);
      }
      const int pb = t & 1;
      #pragma unroll
      for (int g=0;g<4;++g) part[pb][wv][g][lane] = acc[g];
      __syncthreads();

      f32x4 r_[4];
      #pragma unroll
      for (int g=0;g<4;++g){
        f32x4 s0 = part[pb][0][g][lane];
        f32x4 s1 = part[pb][1][g][lane];
        f32x4 s2 = part[pb][2][g][lane];
        f32x4 s3 = part[pb][3][g][lane];
        r_[g] = (s0 + s1) + (s2 + s3);
      }

      float hvv[4];
      {
        const int r = wv;
        float pf = r_[0][r] + b2f((unsigned short)xq[0][r]) + bias[0];
        float pi = r_[1][r] + b2f((unsigned short)xq[1][r]) + bias[1];
        float pz = r_[2][r] + b2f((unsigned short)xq[2][r]) + bias[2];
        float po = r_[3][r] + b2f((unsigned short)xq[3][r]) + bias[3];
        float fg = sigm(pf), ig = sigm(pi), zg = tanh_(pz), og = sigm(po);
        float cn = fg*cst[r] + ig*zg;
        cst[r] = cn;
        hv = og * tanh_(cn);
        hvv[r] = hv;
        unsigned m  = (unsigned)f2b(hv);
        unsigned nb = (unsigned)__shfl_xor(m, 1);
        if ((l15 & 1) == 0){
          unsigned word = m | (nb << 16);
          unsigned* pw = hsw + (size_t)(t+1)*8192 + (size_t)(lg*4+wv)*512 + (n >> 1);
          st_u32_mall(pw, word);
        }
      }
      #pragma unroll
      for (int r=0;r<4;++r){
        if (r == wv) continue;
        float pf = r_[0][r] + b2f((unsigned short)xq[0][r]) + bias[0];
        float pi = r_[1][r] + b2f((unsigned short)xq[1][r]) + bias[1];
        float pz = r_[2][r] + b2f((unsigned short)xq[2][r]) + bias[2];
        float po = r_[3][r] + b2f((unsigned short)xq[3][r]) + bias[3];
        float fg = sigm(pf), ig = sigm(pi), zg = tanh_(pz), og = sigm(po);
        float cn = fg*cst[r] + ig*zg;
        cst[r] = cn;
        hvv[r] = og * tanh_(cn);
      }
      if (t == 1023 && wv == 0){
        #pragma unroll
        for (int r=0;r<4;++r){
          oc[(size_t)(lg*4+r)*1024 + n] = cst[r];
          oh[(size_t)(lg*4+r)*1024 + n] = hvv[r];
        }
      }
    }
    return;
  }

  // ==================== xproj + post (WGs 64..255) ====================
  unsigned short* AsmB = (unsigned short*)smem;            // [128*32]
  unsigned short* BsmB = (unsigned short*)(smem + 8192);   // [128*32]
  const int wid = blockIdx.x - 64;
  const int wy = wv >> 1, wx = wv & 1;
  const int rr = tid >> 1, kq = tid & 1;
  const int s0 = kq*2;
  unsigned short* aw0 = &AsmB[rr*32 + (((s0  ) ^ (rr&3))<<3)];
  unsigned short* aw1 = &AsmB[rr*32 + (((s0+1) ^ (rr&3))<<3)];
  unsigned short* bw0 = &BsmB[rr*32 + (((s0  ) ^ (rr&3))<<3)];
  unsigned short* bw1 = &BsmB[rr*32 + (((s0+1) ^ (rr&3))<<3)];

  // ---- xproj tiles: idx = tm*32 + tn*4 + g, tm-major ----
  for (int idx = wid; idx < 4096; idx += 192){
    const int tm = idx >> 5, rmn = idx & 31, tn = rmn >> 2, g = rmn & 3;
    const float* X  = (g==0)?xF:(g==1)?xI:(g==2)?xZ:xO;
    const float* Bp = (g==0)?bF:(g==1)?bI:(g==2)?bZ:bO;
    const unsigned short* Wg = wt + (size_t)g*1048576;

    const int ar = tm*128 + rr;
    const int ab = ar & 15, as_ = ar >> 4;
    const float* aptr = X + ((size_t)ab*1024 + as_)*1024 + kq*16;
    const unsigned short* bp_ = Wg + (size_t)(tn*128 + rr)*1024 + kq*16;

    f32x4 acc[4][4];
    #pragma unroll
    for (int m=0;m<4;++m)
      #pragma unroll
      for (int q=0;q<4;++q) acc[m][q] = (f32x4){0.f,0.f,0.f,0.f};

    for (int k0=0; k0<1024; k0+=32){
      const float* ap = aptr + k0;
      f32x4 v0 = *(const f32x4*)(ap + 0);
      f32x4 v1 = *(const f32x4*)(ap + 4);
      f32x4 v2 = *(const f32x4*)(ap + 8);
      f32x4 v3 = *(const f32x4*)(ap + 12);
      ushort8_t pa, pb;
      #pragma unroll
      for (int j=0;j<4;++j){ pa[j]=f2b(v0[j]); pa[4+j]=f2b(v1[j]); pb[j]=f2b(v2[j]); pb[4+j]=f2b(v3[j]); }
      *(ushort8_t*)aw0 = pa;
      *(ushort8_t*)aw1 = pb;
      ushort8_t q0 = *(const ushort8_t*)(bp_ + k0);
      ushort8_t q1 = *(const ushort8_t*)(bp_ + k0 + 8);
      *(ushort8_t*)bw0 = q0;
      *(ushort8_t*)bw1 = q1;
      __syncthreads();

      short8 af[4], bf_[4];
      #pragma unroll
      for (int m=0;m<4;++m){
        int row = wy*64 + m*16 + l15;
        af[m] = *(const short8*)&AsmB[row*32 + ((lg ^ (row&3))<<3)];
      }
      #pragma unroll
      for (int q=0;q<4;++q){
        int row = wx*64 + q*16 + l15;
        bf_[q] = *(const short8*)&BsmB[row*32 + ((lg ^ (row&3))<<3)];
      }
      #pragma unroll
      for (int m=0;m<4;++m)
        #pragma unroll
        for (int q=0;q<4;++q)
          acc[m][q] = __builtin_amdgcn_mfma_f32_16x16x32_bf16(af[m], bf_[q], acc[m][q], 0,0,0);
      __syncthreads();
    }

    #pragma unroll
    for (int m=0;m<4;++m){
      const int t = tm*8 + wy*4 + m;
      #pragma unroll
      for (int q=0;q<4;++q){
        const int n = tn*128 + wx*64 + q*16 + l15;
        const float bias = Bp[n];
        f32x4 v = acc[m][q];
        ushort4_t pk;
        #pragma unroll
        for (int r=0;r<4;++r) pk[r] = f2b(v[r] + bias);
        uint2_t w2 = __builtin_bit_cast(uint2_t, pk);
        unsigned short* dst = xg + (size_t)((t*4+g)*1024 + n)*16 + lg*4;
        asm volatile("global_store_dwordx2 %0, %1, off sc0 sc1"
                     :: "v"(dst), "v"(w2) : "memory");
      }
    }
  }

  // ---- post tiles: idx = tm*8 + tn, tm-major; A staging gated on hs ----
  for (int idx = wid; idx < 1024; idx += 192){
    const int tm = idx >> 3, tn = idx & 7;
    const unsigned short* aptr = hs + 16384 + (size_t)(tm*128 + rr)*1024 + kq*16;
    const unsigned short* bp_  = wt + (size_t)4*1048576 + (size_t)(tn*128 + rr)*1024 + kq*16;

    f32x4 acc[4][4];
    #pragma unroll
    for (int m=0;m<4;++m)
      #pragma unroll
      for (int q=0;q<4;++q) acc[m][q] = (f32x4){0.f,0.f,0.f,0.f};

    for (int k0=0; k0<1024; k0+=32){
      ushort8_t a0, a1;
      asm volatile(
        "global_load_dwordx4 %0, %2, off\n\t"
        "global_load_dwordx4 %1, %3, off\n\t"
        "s_waitcnt vmcnt(0)"
        : "=&v"(a0), "=&v"(a1)
        : "v"(aptr + k0), "v"(aptr + k0 + 8) : "memory");
      __builtin_amdgcn_sched_barrier(0);
      {
        uint4_t q0 = __builtin_bit_cast(uint4_t, a0);
        uint4_t q1 = __builtin_bit_cast(uint4_t, a1);
        bool b0 = (q0[0]==SENT)||(q0[1]==SENT)||(q0[2]==SENT)||(q0[3]==SENT);
        bool b1 = (q1[0]==SENT)||(q1[1]==SENT)||(q1[2]==SENT)||(q1[3]==SENT);
        while (__any(b0 | b1)){
          __builtin_amdgcn_s_sleep(8);
          if (b0) asm volatile("global_load_dwordx4 %0, %1, off sc0 sc1"
                               : "+v"(a0) : "v"(aptr + k0) : "memory");
          if (b1) asm volatile("global_load_dwordx4 %0, %1, off sc0 sc1"
                               : "+v"(a1) : "v"(aptr + k0 + 8) : "memory");
          asm volatile("s_waitcnt vmcnt(0)" ::: "memory");
          __builtin_amdgcn_sched_barrier(0);
          q0 = __builtin_bit_cast(uint4_t, a0);
          q1 = __builtin_bit_cast(uint4_t, a1);
          b0 = (q0[0]==SENT)||(q0[1]==SENT)||(q0[2]==SENT)||(q0[3]==SENT);
          b1 = (q1[0]==SENT)||(q1[1]==SENT)||(q1[2]==SENT)||(q1[3]==SENT);
        }
      }
      *(ushort8_t*)aw0 = a0;
      *(ushort8_t*)aw1 = a1;
      ushort8_t q0v = *(const ushort8_t*)(bp_ + k0);
      ushort8_t q1v = *(const ushort8_t*)(bp_ + k0 + 8);
      *(ushort8_t*)bw0 = q0v;
      *(ushort8_t*)bw1 = q1v;
      __syncthreads();

      short8 af[4], bf_[4];
      #pragma unroll
      for (int m=0;m<4;++m){
        int row = wy*64 + m*16 + l15;
        af[m] = *(const short8*)&AsmB[row*32 + ((lg ^ (row&3))<<3)];
      }
      #pragma unroll
      for (int q=0;q<4;++q){
        int row = wx*64 + q*16 + l15;
        bf_[q] = *(const short8*)&BsmB[row*32 + ((lg ^ (row&3))<<3)];
      }
      #pragma unroll
      for (int m=0;m<4;++m)
        #pragma unroll
        for (int q=0;q<4;++q)
          acc[m][q] = __builtin_amdgcn_mfma_f32_16x16x32_bf16(af[m], bf_[q], acc[m][q], 0,0,0);
      __syncthreads();
    }

    #pragma unroll
    for (int m=0;m<4;++m){
      const int s = tm*8 + wy*4 + m;
      #pragma unroll
      for (int q=0;q<4;++q){
        const int n = tn*128 + wx*64 + q*16 + l15;
        const float bias = bpost[n];
        f32x4 v = acc[m][q];
        #pragma unroll
        for (int r=0;r<4;++r){
          const int b = lg*4 + r;
          y[((size_t)b << 20) + ((size_t)s << 10) + n] = v[r] + bias;
        }
      }
    }
  }
}

extern "C" void kernel_launch(void* const* d_in, const int* in_sizes, int n_in,
                              void* d_out, int out_size, void* d_ws, size_t ws_size,
                              hipStream_t stream)
{
  const float* f_in = (const float*)d_in[0];
  const float* i_in = (const float*)d_in[1];
  const float* z_in = (const float*)d_in[2];
  const float* o_in = (const float*)d_in[3];
  const float* c0   = (const float*)d_in[4];
  const float* h0   = (const float*)d_in[5];
  const float* W_Fx = (const float*)d_in[6];  const float* b_Fx = (const float*)d_in[7];
  const float* W_Ix = (const float*)d_in[8];  const float* b_Ix = (const float*)d_in[9];
  const float* W_Zx = (const float*)d_in[10]; const float* b_Zx = (const float*)d_in[11];
  const float* W_Ox = (const float*)d_in[12]; const float* b_Ox = (const float*)d_in[13];
  const float* W_Fh = (const float*)d_in[14]; const float* b_Fh = (const float*)d_in[15];
  const float* W_Ih = (const float*)d_in[16]; const float* b_Ih = (const float*)d_in[17];
  const float* W_Zh = (const float*)d_in[18]; const float* b_Zh = (const float*)d_in[19];
  const float* W_Oh = (const float*)d_in[20]; const float* b_Oh = (const float*)d_in[21];
  const float* W_post = (const float*)d_in[22]; const float* b_post = (const float*)d_in[23];

  char* ws = (char*)d_ws;
  unsigned short* xg = (unsigned short*)(ws);
  unsigned short* hs = (unsigned short*)(ws + XG_BYTES);
  unsigned short* wt = (unsigned short*)(ws + WT_OFF);

  float* y  = (float*)d_out;
  float* oc = y + 16777216;   // 16*1024*1024
  float* oh = oc + 16384;

  k_prep<<<dim3(16,16,9), 256, 0, stream>>>(W_Fx, W_Ix, W_Zx, W_Ox, W_post,
                                            W_Fh, W_Ih, W_Zh, W_Oh, wt);
  k_init<<<64, 256, 0, stream>>>(h0, hs);
  k_fill<<<40960, 256, 0, stream>>>((unsigned*)xg, (unsigned*)hs);
  k_mega<<<256, 256, 0, stream>>>(f_in, i_in, z_in, o_in,
                                  b_Fx, b_Ix, b_Zx, b_Ox,
                                  wt,
                                  b_Fh, b_Ih, b_Zh, b_Oh,
                                  c0, xg, hs, b_post, y, oc, oh);
}